// Round 10
// baseline (160.550 us; speedup 1.0000x reference)
//
#include <hip/hip_runtime.h>
#include <hip/hip_bf16.h>

#define N_TOKENS 8192
#define IN_FEAT 1024
#define OUT_FEAT 1024
#define NUM_EXPERT 8

#define BM 128
#define BN 128
#define BK 32

typedef __bf16 bf16x8 __attribute__((ext_vector_type(8)));
typedef float f32x4 __attribute__((ext_vector_type(4)));

// fp32 -> bf16 round-to-nearest-even, two packed into one dword.
__device__ __forceinline__ unsigned int rne16(float x) {
    union { float f; unsigned int u; } c;
    c.f = x;
    unsigned int u = c.u;
    u += 0x7fffu + ((u >> 16) & 1u);
    return u >> 16;
}
__device__ __forceinline__ unsigned int pk2(float x, float y) {
    return rne16(x) | (rne16(y) << 16);
}

// async global->LDS, 16 B per lane; LDS dest is wave-uniform base + lane*16.
__device__ __forceinline__ void load_lds16(const void* g, void* l) {
    __builtin_amdgcn_global_load_lds(
        (const __attribute__((address_space(1))) unsigned int*)g,
        (__attribute__((address_space(3))) unsigned int*)l,
        16, 0, 0);
}

// ---- k1: fused histogram + scan + scatter (single block, 1024 thr) ----
__global__ __launch_bounds__(1024) void moe_sort(const int* __restrict__ gate,
                                                 int* __restrict__ seg,
                                                 int* __restrict__ perm) {
    __shared__ int lc[NUM_EXPERT];
    __shared__ int cur[NUM_EXPERT];
    const int t = threadIdx.x;
    const int lane = t & 63;
    const unsigned long long lt = (lane == 0) ? 0ull : (~0ull >> (64 - lane));

    if (t < NUM_EXPERT) lc[t] = 0;
    __syncthreads();

    int gv[8];
    #pragma unroll
    for (int i = 0; i < 8; ++i) gv[i] = gate[t + i * 1024];

    #pragma unroll
    for (int i = 0; i < 8; ++i) {
        #pragma unroll
        for (int e = 0; e < NUM_EXPERT; ++e) {
            unsigned long long m = __ballot(gv[i] == e);
            if (lane == 0 && m) atomicAdd(&lc[e], __popcll(m));
        }
    }
    __syncthreads();
    if (t == 0) {
        int s = 0;
        #pragma unroll
        for (int e = 0; e < NUM_EXPERT; ++e) { seg[e] = s; cur[e] = s; s += lc[e]; }
        seg[NUM_EXPERT] = s;
    }
    __syncthreads();

    #pragma unroll
    for (int i = 0; i < 8; ++i) {
        const int g = gv[i];
        const int idx = t + i * 1024;
        #pragma unroll
        for (int e = 0; e < NUM_EXPERT; ++e) {
            unsigned long long m = __ballot(g == e);
            if (g == e) {
                int rank = __popcll(m & lt);
                int leader = (int)__ffsll((unsigned long long)m) - 1;
                int p0 = 0;
                if (rank == 0) p0 = atomicAdd(&cur[e], __popcll(m));
                p0 = __shfl(p0, leader);
                perm[p0 + rank] = idx;
            }
        }
    }
}

// ---- k2: bf16 convert; A gathered in perm order (A2[r] = inp[perm[r]]),
//          4096 blocks x 4 rows (1 row/wave), 16 B stores ----
__global__ __launch_bounds__(256) void moe_prep(const float* __restrict__ inp,
                                                const float* __restrict__ weight,
                                                const int* __restrict__ perm,
                                                unsigned int* __restrict__ A2,
                                                unsigned int* __restrict__ W2) {
    const int bid = blockIdx.x;
    const int t = threadIdx.x;
    const int wave = t >> 6, lane = t & 63;
    const float* src;
    unsigned int* dst;
    if (bid < 2048) {
        int row = bid * 4 + wave;
        src = inp + perm[row] * IN_FEAT;
        dst = A2 + row * (IN_FEAT / 2);
    } else {
        int row = (bid - 2048) * 4 + wave;
        src = weight + row * IN_FEAT;
        dst = W2 + row * (IN_FEAT / 2);
    }
    #pragma unroll
    for (int ps = 0; ps < 2; ++ps) {
        float4 v0 = *(const float4*)(src + ps * 512 + lane * 8);
        float4 v1 = *(const float4*)(src + ps * 512 + lane * 8 + 4);
        uint4 o;
        o.x = pk2(v0.x, v0.y); o.y = pk2(v0.z, v0.w);
        o.z = pk2(v1.x, v1.y); o.w = pk2(v1.z, v1.w);
        *(uint4*)(dst + ps * 256 + lane * 4) = o;
    }
}

// ---- k3: bf16 grouped GEMM. 128x128 block tile, TWO waves of 64x128 each
// (LDS->VGPR amplification 1.5 vs 2.0 for 2x2 64x64 -> higher MFMA ceiling).
// dbuf DMA pipeline; bid = mtile*64 + ntile*8 + e pins expert e to XCD e.
__global__ __launch_bounds__(128, 2) void moe_gemm(
    const unsigned short* __restrict__ A2,   // bf16 [8192][1024], perm order
    const unsigned short* __restrict__ W2,   // bf16 [8][1024][1024]
    const int* __restrict__ perm,
    const int* __restrict__ seg,
    float* __restrict__ out) {

    const int bid = blockIdx.x;
    const int e = bid & 7;
    const int ntile = (bid >> 3) & 7;
    const int mtile = bid >> 6;

    const int base = seg[e];
    const int cnt = seg[e + 1] - base;
    if (mtile * BM >= cnt) return;
    const int tbase = base + mtile * BM;
    int rows = cnt - mtile * BM; if (rows > BM) rows = BM;

    __shared__ __align__(16) unsigned short lA[2][BM * BK];   // 2 x 8 KB
    __shared__ __align__(16) unsigned short lB[2][BN * BK];   // 2 x 8 KB

    const int t = threadIdx.x;            // 0..127
    const int wave = t >> 6;
    const int lane = t & 63;

    // staging: 1024 16-B chunks per slab (512 A + 512 B).
    // chunk c (0..511): row = c>>2, k-part p = (c&3)^(row&3) [XOR swizzle].
    // thread t covers chunks c = j*128 + t for j=0..3 on A and on B.
    const unsigned short* srcA[4];
    const unsigned short* srcB[4];
    int ldsOfs[4];
    #pragma unroll
    for (int j = 0; j < 4; ++j) {
        const int c = j * 128 + t;
        const int r = c >> 2;
        const int p = (c & 3) ^ (r & 3);
        int ar = tbase + r; if (ar > N_TOKENS - 1) ar = N_TOKENS - 1;
        srcA[j] = A2 + ar * IN_FEAT + p * 8;
        srcB[j] = W2 + e * (OUT_FEAT * IN_FEAT) + (ntile * BN + r) * IN_FEAT + p * 8;
        ldsOfs[j] = c * 8;  // shorts
    }

    // fragment read addresses (swizzle-matched): wave covers rows wave*64..+63,
    // all 128 cols. row stride 32 shorts (64 B), qx = quad ^ (l15&3).
    const int l15 = lane & 15;
    const int quad = lane >> 4;
    const int qx = quad ^ (l15 & 3);
    const int fofsA = (wave * 64 + l15) * BK + qx * 8;
    const int fofsB = l15 * BK + qx * 8;

    f32x4 acc[4][8];
    #pragma unroll
    for (int i = 0; i < 4; ++i)
        #pragma unroll
        for (int j = 0; j < 8; ++j)
            acc[i][j] = (f32x4)0.0f;

#define ISSUE(buf, kofs) do {                                          \
        _Pragma("unroll")                                              \
        for (int j = 0; j < 4; ++j) {                                  \
            load_lds16(srcA[j] + (kofs), &lA[buf][ldsOfs[j]]);         \
            load_lds16(srcB[j] + (kofs), &lB[buf][ldsOfs[j]]);         \
        }                                                              \
    } while (0)

#define COMPUTE(buf) do {                                              \
        bf16x8 af[4], bq[8];                                           \
        _Pragma("unroll")                                              \
        for (int i = 0; i < 4; ++i)                                    \
            af[i] = *(const bf16x8*)&lA[buf][fofsA + i * 16 * BK];     \
        _Pragma("unroll")                                              \
        for (int j = 0; j < 8; ++j)                                    \
            bq[j] = *(const bf16x8*)&lB[buf][fofsB + j * 16 * BK];     \
        _Pragma("unroll")                                              \
        for (int i = 0; i < 4; ++i)                                    \
            _Pragma("unroll")                                          \
            for (int j = 0; j < 8; ++j)                                \
                acc[i][j] = __builtin_amdgcn_mfma_f32_16x16x32_bf16(   \
                    af[i], bq[j], acc[i][j], 0, 0, 0);                 \
    } while (0)

    // prologue: slab 0 -> buf0
    ISSUE(0, 0);

    #pragma unroll 1
    for (int kk = 0; kk < 16; ++kk) {
        const int k0 = kk * 64;  // shorts; slab 2kk at k0, slab 2kk+1 at k0+32

        __syncthreads();              // drain DMA(2kk) + prev reads
        ISSUE(1, k0 + 32);            // slab 2kk+1 -> buf1, overlaps compute
        COMPUTE(0);

        __syncthreads();              // drain DMA(2kk+1) + buf0 reads
        if (kk < 15) ISSUE(0, k0 + 64);
        COMPUTE(1);
    }
#undef COMPUTE
#undef ISSUE

    // epilogue: C/D layout col=lane&15, row=quad*4+reg
    #pragma unroll
    for (int mi = 0; mi < 4; ++mi) {
        #pragma unroll
        for (int r = 0; r < 4; ++r) {
            int row = wave * 64 + mi * 16 + quad * 4 + r;
            if (row < rows) {
                int token = perm[tbase + row];
                float* op = out + token * OUT_FEAT + ntile * BN;
                #pragma unroll
                for (int ni = 0; ni < 8; ++ni)
                    op[ni * 16 + l15] = acc[mi][ni][r];
            }
        }
    }
}

// ---- fallback (fused-convert gemm) if ws can't hold bf16 copies ----
#define FLDSW 20
__global__ __launch_bounds__(256, 4) void moe_gemm_fb(
    const float* __restrict__ inp,
    const float* __restrict__ weight,
    const int* __restrict__ perm,
    const int* __restrict__ seg,
    float* __restrict__ out) {

    const int bid = blockIdx.x;
    const int mtile = bid >> 7;
    const int e = (bid >> 4) & 7;
    const int ntile = bid & 15;

    const int base = seg[e];
    const int cnt = seg[e + 1] - base;
    if (mtile * 128 >= cnt) return;

    __shared__ unsigned int lA[128 * FLDSW];
    __shared__ unsigned int lB[64 * FLDSW];
    __shared__ int rowids[128];

    const int t = threadIdx.x;
    if (t < 128) {
        int r = mtile * 128 + t;
        rowids[t] = (r < cnt) ? perm[base + r] : -1;
    }
    __syncthreads();

    const int srow = t >> 1;
    const int scol = (t & 1) << 4;
    const int tokA = rowids[srow];
    const bool aval = (tokA >= 0);
    const float* aptr = inp + (aval ? tokA : 0) * IN_FEAT + scol;
    const int sdstA = srow * FLDSW + (scol >> 1);
    const int browB = t >> 2;
    const int bcol = (t & 3) << 3;
    const float* bptr = weight + e * (OUT_FEAT * IN_FEAT)
                        + (ntile * 64 + browB) * IN_FEAT + bcol;
    const int sdstB = browB * FLDSW + (bcol >> 1);

    const int wave = t >> 6;
    const int lane = t & 63;
    const int wm = (wave & 1) << 6;
    const int wn = (wave >> 1) << 5;
    const int l15 = lane & 15;
    const int quad = lane >> 4;

    f32x4 acc[4][2];
    #pragma unroll
    for (int i = 0; i < 4; ++i)
        #pragma unroll
        for (int j = 0; j < 2; ++j)
            acc[i][j] = (f32x4)0.0f;

    float4 ra[4], rb[2];
    {
        const float4* ap = (const float4*)aptr;
        const float4* bp = (const float4*)bptr;
        #pragma unroll
        for (int i = 0; i < 4; ++i) ra[i] = ap[i];
        #pragma unroll
        for (int i = 0; i < 2; ++i) rb[i] = bp[i];
    }

    for (int k0 = 0; k0 < IN_FEAT; k0 += 32) {
        unsigned int ua[8], ub[4];
        #pragma unroll
        for (int i = 0; i < 4; ++i) {
            ua[2 * i]     = pk2(ra[i].x, ra[i].y);
            ua[2 * i + 1] = pk2(ra[i].z, ra[i].w);
        }
        #pragma unroll
        for (int i = 0; i < 2; ++i) {
            ub[2 * i]     = pk2(rb[i].x, rb[i].y);
            ub[2 * i + 1] = pk2(rb[i].z, rb[i].w);
        }
        if (!aval) {
            #pragma unroll
            for (int i = 0; i < 8; ++i) ua[i] = 0u;
        }

        __syncthreads();
        *(uint4*)&lA[sdstA]     = make_uint4(ua[0], ua[1], ua[2], ua[3]);
        *(uint4*)&lA[sdstA + 4] = make_uint4(ua[4], ua[5], ua[6], ua[7]);
        *(uint4*)&lB[sdstB]     = make_uint4(ub[0], ub[1], ub[2], ub[3]);
        __syncthreads();

        if (k0 + 32 < IN_FEAT) {
            const float4* ap = (const float4*)(aptr + k0 + 32);
            const float4* bp = (const float4*)(bptr + k0 + 32);
            #pragma unroll
            for (int i = 0; i < 4; ++i) ra[i] = ap[i];
            #pragma unroll
            for (int i = 0; i < 2; ++i) rb[i] = bp[i];
        }

        bf16x8 af[4], bq[2];
        #pragma unroll
        for (int i = 0; i < 4; ++i)
            af[i] = *(const bf16x8*)&lA[(wm + i * 16 + l15) * FLDSW + (quad << 2)];
        #pragma unroll
        for (int j = 0; j < 2; ++j)
            bq[j] = *(const bf16x8*)&lB[(wn + j * 16 + l15) * FLDSW + (quad << 2)];

        #pragma unroll
        for (int i = 0; i < 4; ++i)
            #pragma unroll
            for (int j = 0; j < 2; ++j)
                acc[i][j] = __builtin_amdgcn_mfma_f32_16x16x32_bf16(
                    af[i], bq[j], acc[i][j], 0, 0, 0);
    }

    #pragma unroll
    for (int mi = 0; mi < 4; ++mi) {
        #pragma unroll
        for (int r = 0; r < 4; ++r) {
            int row = wm + mi * 16 + quad * 4 + r;
            int token = rowids[row];
            if (token >= 0) {
                float* op = out + token * OUT_FEAT + ntile * 64 + wn;
                #pragma unroll
                for (int ni = 0; ni < 2; ++ni)
                    op[ni * 16 + l15] = acc[mi][ni][r];
            }
        }
    }
}

extern "C" void kernel_launch(void* const* d_in, const int* in_sizes, int n_in,
                              void* d_out, int out_size, void* d_ws, size_t ws_size,
                              hipStream_t stream) {
    const float* inp = (const float*)d_in[0];
    const int* gate = (const int*)d_in[1];
    const float* weight = (const float*)d_in[2];
    float* out = (float*)d_out;

    int* perm = (int*)d_ws;           // 8192 ints
    int* seg = perm + N_TOKENS;       // 9 (pad 16)

    const size_t need = 65536 + 2ull * N_TOKENS * IN_FEAT * 2;  // 33.6 MB
    const int useBf16 = (ws_size >= need);
    unsigned int* A2 = (unsigned int*)((char*)d_ws + 65536);
    unsigned int* W2 = A2 + (N_TOKENS * IN_FEAT / 2);

    moe_sort<<<1, 1024, 0, stream>>>(gate, seg, perm);

    if (useBf16) {
        moe_prep<<<4096, 256, 0, stream>>>(inp, weight, perm, A2, W2);
        // bid = mtile*64 + ntile*8 + e ; 64 mtiles x 8 ntiles x 8 experts
        moe_gemm<<<4096, 128, 0, stream>>>((const unsigned short*)A2,
                                           (const unsigned short*)W2,
                                           perm, seg, out);
    } else {
        moe_gemm_fb<<<8192, 256, 0, stream>>>(inp, weight, perm, seg, out);
    }
}

// Round 11
// 155.260 us; speedup vs baseline: 1.0341x; 1.0341x over previous
//
#include <hip/hip_runtime.h>
#include <hip/hip_bf16.h>

#define N_TOKENS 8192
#define IN_FEAT 1024
#define OUT_FEAT 1024
#define NUM_EXPERT 8

#define BM 128
#define BN 128
#define BK 32

typedef __bf16 bf16x8 __attribute__((ext_vector_type(8)));
typedef float f32x4 __attribute__((ext_vector_type(4)));

// fp32 -> bf16 round-to-nearest-even, two packed into one dword.
__device__ __forceinline__ unsigned int rne16(float x) {
    union { float f; unsigned int u; } c;
    c.f = x;
    unsigned int u = c.u;
    u += 0x7fffu + ((u >> 16) & 1u);
    return u >> 16;
}
__device__ __forceinline__ unsigned int pk2(float x, float y) {
    return rne16(x) | (rne16(y) << 16);
}

// async global->LDS, 16 B per lane; LDS dest is wave-uniform base + lane*16.
__device__ __forceinline__ void load_lds16(const void* g, void* l) {
    __builtin_amdgcn_global_load_lds(
        (const __attribute__((address_space(1))) unsigned int*)g,
        (__attribute__((address_space(3))) unsigned int*)l,
        16, 0, 0);
}

// ---- k1: fused histogram + scan + scatter (single block, 1024 thr) ----
__global__ __launch_bounds__(1024) void moe_sort(const int* __restrict__ gate,
                                                 int* __restrict__ seg,
                                                 int* __restrict__ perm) {
    __shared__ int lc[NUM_EXPERT];
    __shared__ int cur[NUM_EXPERT];
    const int t = threadIdx.x;
    const int lane = t & 63;
    const unsigned long long lt = (lane == 0) ? 0ull : (~0ull >> (64 - lane));

    if (t < NUM_EXPERT) lc[t] = 0;
    __syncthreads();

    int gv[8];
    #pragma unroll
    for (int i = 0; i < 8; ++i) gv[i] = gate[t + i * 1024];

    #pragma unroll
    for (int i = 0; i < 8; ++i) {
        #pragma unroll
        for (int e = 0; e < NUM_EXPERT; ++e) {
            unsigned long long m = __ballot(gv[i] == e);
            if (lane == 0 && m) atomicAdd(&lc[e], __popcll(m));
        }
    }
    __syncthreads();
    if (t == 0) {
        int s = 0;
        #pragma unroll
        for (int e = 0; e < NUM_EXPERT; ++e) { seg[e] = s; cur[e] = s; s += lc[e]; }
        seg[NUM_EXPERT] = s;
    }
    __syncthreads();

    #pragma unroll
    for (int i = 0; i < 8; ++i) {
        const int g = gv[i];
        const int idx = t + i * 1024;
        #pragma unroll
        for (int e = 0; e < NUM_EXPERT; ++e) {
            unsigned long long m = __ballot(g == e);
            if (g == e) {
                int rank = __popcll(m & lt);
                int leader = (int)__ffsll((unsigned long long)m) - 1;
                int p0 = 0;
                if (rank == 0) p0 = atomicAdd(&cur[e], __popcll(m));
                p0 = __shfl(p0, leader);
                perm[p0 + rank] = idx;
            }
        }
    }
}

// ---- k2: bf16 convert; A gathered in perm order (A2[r] = inp[perm[r]]),
//          4096 blocks x 4 rows (1 row/wave), 16 B stores ----
__global__ __launch_bounds__(256) void moe_prep(const float* __restrict__ inp,
                                                const float* __restrict__ weight,
                                                const int* __restrict__ perm,
                                                unsigned int* __restrict__ A2,
                                                unsigned int* __restrict__ W2) {
    const int bid = blockIdx.x;
    const int t = threadIdx.x;
    const int wave = t >> 6, lane = t & 63;
    const float* src;
    unsigned int* dst;
    if (bid < 2048) {
        int row = bid * 4 + wave;
        src = inp + perm[row] * IN_FEAT;
        dst = A2 + row * (IN_FEAT / 2);
    } else {
        int row = (bid - 2048) * 4 + wave;
        src = weight + row * IN_FEAT;
        dst = W2 + row * (IN_FEAT / 2);
    }
    #pragma unroll
    for (int ps = 0; ps < 2; ++ps) {
        float4 v0 = *(const float4*)(src + ps * 512 + lane * 8);
        float4 v1 = *(const float4*)(src + ps * 512 + lane * 8 + 4);
        uint4 o;
        o.x = pk2(v0.x, v0.y); o.y = pk2(v0.z, v0.w);
        o.z = pk2(v1.x, v1.y); o.w = pk2(v1.z, v1.w);
        *(uint4*)(dst + ps * 256 + lane * 4) = o;
    }
}

// ---- k3: bf16 grouped GEMM: dbuf DMA pipeline, 128x128, BK=32, 4 waves.
// bid = mtile*64 + ntile*8 + e  =>  bid%8 = e pins each expert's blocks (and
// every A-tile's 8 ntile-sharers) to one XCD: 2 MB of W2 + live A-tiles stay
// L2-resident. Low-mtile bids are active for all experts -> dense dispatch.
__global__ __launch_bounds__(256, 4) void moe_gemm(
    const unsigned short* __restrict__ A2,   // bf16 [8192][1024], perm order
    const unsigned short* __restrict__ W2,   // bf16 [8][1024][1024]
    const int* __restrict__ perm,
    const int* __restrict__ seg,
    float* __restrict__ out) {

    const int bid = blockIdx.x;
    const int e = bid & 7;
    const int ntile = (bid >> 3) & 7;
    const int mtile = bid >> 6;

    const int base = seg[e];
    const int cnt = seg[e + 1] - base;
    if (mtile * BM >= cnt) return;
    const int tbase = base + mtile * BM;
    int rows = cnt - mtile * BM; if (rows > BM) rows = BM;

    __shared__ __align__(16) unsigned short lA[2][BM * BK];   // 2 x 8 KB
    __shared__ __align__(16) unsigned short lB[2][BN * BK];   // 2 x 8 KB

    const int t = threadIdx.x;

    // staging: chunk c in {t, t+256}: row = c>>2, k-part p = (c&3)^(row&3)
    const int crow = t >> 2;                 // 0..63
    const int p = (t & 3) ^ (crow & 3);
    int ar0 = tbase + crow;       if (ar0 > N_TOKENS - 1) ar0 = N_TOKENS - 1;
    int ar1 = tbase + 64 + crow;  if (ar1 > N_TOKENS - 1) ar1 = N_TOKENS - 1;
    const unsigned short* gA0 = A2 + ar0 * IN_FEAT + p * 8;
    const unsigned short* gA1 = A2 + ar1 * IN_FEAT + p * 8;
    const unsigned short* gB0 = W2 + e * (OUT_FEAT * IN_FEAT)
                                + (ntile * BN + crow) * IN_FEAT + p * 8;
    const unsigned short* gB1 = gB0 + 64 * IN_FEAT;
    const int dofs = t * 8;                  // chunk t
    const int dofs2 = (t + 256) * 8;         // chunk t+256

    // fragment read addresses (swizzle-matched)
    const int wave = t >> 6;
    const int lane = t & 63;
    const int wm = (wave & 1) << 6;
    const int wn = (wave >> 1) << 6;
    const int l15 = lane & 15;
    const int quad = lane >> 4;
    const int qx = quad ^ (l15 & 3);
    const int fofsA = (wm + l15) * BK + qx * 8;
    const int fofsB = (wn + l15) * BK + qx * 8;

    f32x4 acc[4][4];
    #pragma unroll
    for (int i = 0; i < 4; ++i)
        #pragma unroll
        for (int j = 0; j < 4; ++j)
            acc[i][j] = (f32x4)0.0f;

    // prologue: slab 0 -> buf0
    load_lds16(gA0, &lA[0][dofs]);
    load_lds16(gA1, &lA[0][dofs2]);
    load_lds16(gB0, &lB[0][dofs]);
    load_lds16(gB1, &lB[0][dofs2]);

    #pragma unroll 1
    for (int kk = 0; kk < 16; ++kk) {
        const int k0 = kk * 64;  // shorts; slab 2kk at k0, slab 2kk+1 at k0+32

        __syncthreads();  // drain DMA(2kk) + prev reads
        // issue slab 2kk+1 -> buf1 (overlaps compute of slab 2kk)
        load_lds16(gA0 + k0 + 32, &lA[1][dofs]);
        load_lds16(gA1 + k0 + 32, &lA[1][dofs2]);
        load_lds16(gB0 + k0 + 32, &lB[1][dofs]);
        load_lds16(gB1 + k0 + 32, &lB[1][dofs2]);

        {
            bf16x8 af[4], bq[4];
            #pragma unroll
            for (int i = 0; i < 4; ++i)
                af[i] = *(const bf16x8*)&lA[0][fofsA + i * 16 * BK];
            #pragma unroll
            for (int j = 0; j < 4; ++j)
                bq[j] = *(const bf16x8*)&lB[0][fofsB + j * 16 * BK];
            #pragma unroll
            for (int i = 0; i < 4; ++i)
                #pragma unroll
                for (int j = 0; j < 4; ++j)
                    acc[i][j] = __builtin_amdgcn_mfma_f32_16x16x32_bf16(
                        af[i], bq[j], acc[i][j], 0, 0, 0);
        }

        __syncthreads();  // drain DMA(2kk+1) + buf0 reads
        if (kk < 15) {    // issue slab 2kk+2 -> buf0 (overlaps compute of 2kk+1)
            load_lds16(gA0 + k0 + 64, &lA[0][dofs]);
            load_lds16(gA1 + k0 + 64, &lA[0][dofs2]);
            load_lds16(gB0 + k0 + 64, &lB[0][dofs]);
            load_lds16(gB1 + k0 + 64, &lB[0][dofs2]);
        }

        {
            bf16x8 af[4], bq[4];
            #pragma unroll
            for (int i = 0; i < 4; ++i)
                af[i] = *(const bf16x8*)&lA[1][fofsA + i * 16 * BK];
            #pragma unroll
            for (int j = 0; j < 4; ++j)
                bq[j] = *(const bf16x8*)&lB[1][fofsB + j * 16 * BK];
            #pragma unroll
            for (int i = 0; i < 4; ++i)
                #pragma unroll
                for (int j = 0; j < 4; ++j)
                    acc[i][j] = __builtin_amdgcn_mfma_f32_16x16x32_bf16(
                        af[i], bq[j], acc[i][j], 0, 0, 0);
        }
    }

    // epilogue: C/D layout col=lane&15, row=quad*4+reg
    #pragma unroll
    for (int mi = 0; mi < 4; ++mi) {
        #pragma unroll
        for (int r = 0; r < 4; ++r) {
            int row = wm + mi * 16 + quad * 4 + r;
            if (row < rows) {
                int token = perm[tbase + row];
                float* op = out + token * OUT_FEAT + ntile * BN + wn;
                #pragma unroll
                for (int ni = 0; ni < 4; ++ni)
                    op[ni * 16 + l15] = acc[mi][ni][r];
            }
        }
    }
}

// ---- fallback (fused-convert gemm) if ws can't hold bf16 copies ----
#define FLDSW 20
__global__ __launch_bounds__(256, 4) void moe_gemm_fb(
    const float* __restrict__ inp,
    const float* __restrict__ weight,
    const int* __restrict__ perm,
    const int* __restrict__ seg,
    float* __restrict__ out) {

    const int bid = blockIdx.x;
    const int mtile = bid >> 7;
    const int e = (bid >> 4) & 7;
    const int ntile = bid & 15;

    const int base = seg[e];
    const int cnt = seg[e + 1] - base;
    if (mtile * 128 >= cnt) return;

    __shared__ unsigned int lA[128 * FLDSW];
    __shared__ unsigned int lB[64 * FLDSW];
    __shared__ int rowids[128];

    const int t = threadIdx.x;
    if (t < 128) {
        int r = mtile * 128 + t;
        rowids[t] = (r < cnt) ? perm[base + r] : -1;
    }
    __syncthreads();

    const int srow = t >> 1;
    const int scol = (t & 1) << 4;
    const int tokA = rowids[srow];
    const bool aval = (tokA >= 0);
    const float* aptr = inp + (aval ? tokA : 0) * IN_FEAT + scol;
    const int sdstA = srow * FLDSW + (scol >> 1);
    const int browB = t >> 2;
    const int bcol = (t & 3) << 3;
    const float* bptr = weight + e * (OUT_FEAT * IN_FEAT)
                        + (ntile * 64 + browB) * IN_FEAT + bcol;
    const int sdstB = browB * FLDSW + (bcol >> 1);

    const int wave = t >> 6;
    const int lane = t & 63;
    const int wm = (wave & 1) << 6;
    const int wn = (wave >> 1) << 5;
    const int l15 = lane & 15;
    const int quad = lane >> 4;

    f32x4 acc[4][2];
    #pragma unroll
    for (int i = 0; i < 4; ++i)
        #pragma unroll
        for (int j = 0; j < 2; ++j)
            acc[i][j] = (f32x4)0.0f;

    float4 ra[4], rb[2];
    {
        const float4* ap = (const float4*)aptr;
        const float4* bp = (const float4*)bptr;
        #pragma unroll
        for (int i = 0; i < 4; ++i) ra[i] = ap[i];
        #pragma unroll
        for (int i = 0; i < 2; ++i) rb[i] = bp[i];
    }

    for (int k0 = 0; k0 < IN_FEAT; k0 += 32) {
        unsigned int ua[8], ub[4];
        #pragma unroll
        for (int i = 0; i < 4; ++i) {
            ua[2 * i]     = pk2(ra[i].x, ra[i].y);
            ua[2 * i + 1] = pk2(ra[i].z, ra[i].w);
        }
        #pragma unroll
        for (int i = 0; i < 2; ++i) {
            ub[2 * i]     = pk2(rb[i].x, rb[i].y);
            ub[2 * i + 1] = pk2(rb[i].z, rb[i].w);
        }
        if (!aval) {
            #pragma unroll
            for (int i = 0; i < 8; ++i) ua[i] = 0u;
        }

        __syncthreads();
        *(uint4*)&lA[sdstA]     = make_uint4(ua[0], ua[1], ua[2], ua[3]);
        *(uint4*)&lA[sdstA + 4] = make_uint4(ua[4], ua[5], ua[6], ua[7]);
        *(uint4*)&lB[sdstB]     = make_uint4(ub[0], ub[1], ub[2], ub[3]);
        __syncthreads();

        if (k0 + 32 < IN_FEAT) {
            const float4* ap = (const float4*)(aptr + k0 + 32);
            const float4* bp = (const float4*)(bptr + k0 + 32);
            #pragma unroll
            for (int i = 0; i < 4; ++i) ra[i] = ap[i];
            #pragma unroll
            for (int i = 0; i < 2; ++i) rb[i] = bp[i];
        }

        bf16x8 af[4], bq[2];
        #pragma unroll
        for (int i = 0; i < 4; ++i)
            af[i] = *(const bf16x8*)&lA[(wm + i * 16 + l15) * FLDSW + (quad << 2)];
        #pragma unroll
        for (int j = 0; j < 2; ++j)
            bq[j] = *(const bf16x8*)&lB[(wn + j * 16 + l15) * FLDSW + (quad << 2)];

        #pragma unroll
        for (int i = 0; i < 4; ++i)
            #pragma unroll
            for (int j = 0; j < 2; ++j)
                acc[i][j] = __builtin_amdgcn_mfma_f32_16x16x32_bf16(
                    af[i], bq[j], acc[i][j], 0, 0, 0);
    }

    #pragma unroll
    for (int mi = 0; mi < 4; ++mi) {
        #pragma unroll
        for (int r = 0; r < 4; ++r) {
            int row = wm + mi * 16 + quad * 4 + r;
            int token = rowids[row];
            if (token >= 0) {
                float* op = out + token * OUT_FEAT + ntile * 64 + wn;
                #pragma unroll
                for (int ni = 0; ni < 2; ++ni)
                    op[ni * 16 + l15] = acc[mi][ni][r];
            }
        }
    }
}

extern "C" void kernel_launch(void* const* d_in, const int* in_sizes, int n_in,
                              void* d_out, int out_size, void* d_ws, size_t ws_size,
                              hipStream_t stream) {
    const float* inp = (const float*)d_in[0];
    const int* gate = (const int*)d_in[1];
    const float* weight = (const float*)d_in[2];
    float* out = (float*)d_out;

    int* perm = (int*)d_ws;           // 8192 ints
    int* seg = perm + N_TOKENS;       // 9 (pad 16)

    const size_t need = 65536 + 2ull * N_TOKENS * IN_FEAT * 2;  // 33.6 MB
    const int useBf16 = (ws_size >= need);
    unsigned int* A2 = (unsigned int*)((char*)d_ws + 65536);
    unsigned int* W2 = A2 + (N_TOKENS * IN_FEAT / 2);

    moe_sort<<<1, 1024, 0, stream>>>(gate, seg, perm);

    if (useBf16) {
        moe_prep<<<4096, 256, 0, stream>>>(inp, weight, perm, A2, W2);
        // bid = mtile*64 + ntile*8 + e ; 64 mtiles x 8 ntiles x 8 experts
        moe_gemm<<<4096, 256, 0, stream>>>((const unsigned short*)A2,
                                           (const unsigned short*)W2,
                                           perm, seg, out);
    } else {
        moe_gemm_fb<<<8192, 256, 0, stream>>>(inp, weight, perm, seg, out);
    }
}